// Round 1
// baseline (693.135 us; speedup 1.0000x reference)
//
#include <hip/hip_runtime.h>

#define IN_F 128
#define OUT_F 64

// --- Kernel 1: messages = x @ W.T  (N x 128) @ (128 x 64) -> N x 64 ---
// One wave per row; lane = output feature. W stored transposed in LDS:
// Wt[k*64 + o] -> bank = o%32 -> 2 lanes/bank (free).
__global__ __launch_bounds__(256) void gemm_msg_kernel(
    const float* __restrict__ x, const float* __restrict__ W,
    float* __restrict__ msg, int N)
{
    __shared__ float Wt[IN_F * OUT_F];  // 32 KiB
    for (int i = threadIdx.x; i < IN_F * OUT_F; i += 256) {
        int k = i >> 6, o = i & 63;
        Wt[i] = W[o * IN_F + k];
    }
    __syncthreads();

    const int wave = threadIdx.x >> 6;
    const int lane = threadIdx.x & 63;
    const int rowstride = gridDim.x * 4;

    for (int row = blockIdx.x * 4 + wave; row < N; row += rowstride) {
        const float4* xr = (const float4*)(x + (size_t)row * IN_F);
        float acc = 0.f;
#pragma unroll
        for (int k4 = 0; k4 < IN_F / 4; ++k4) {
            float4 xv = xr[k4];  // uniform across wave -> broadcast, L1/L2 hit
            acc += xv.x * Wt[(k4 * 4 + 0) * OUT_F + lane];
            acc += xv.y * Wt[(k4 * 4 + 1) * OUT_F + lane];
            acc += xv.z * Wt[(k4 * 4 + 2) * OUT_F + lane];
            acc += xv.w * Wt[(k4 * 4 + 3) * OUT_F + lane];
        }
        msg[(size_t)row * OUT_F + lane] = acc;
    }
}

// --- Kernel 2: per-edge attention + scatter-accumulate ---
// One wave per edge (incl. N self-loops appended after the E real edges).
// lane = feature. e = dot(msg[dst], a[:64]) + dot(msg[src], a[64:]),
// w = exp(leaky_relu(e)); atomicAdd into agg[dst] (=d_out) and denom[dst].
__global__ __launch_bounds__(256) void edge_kernel(
    const int* __restrict__ src_arr, const int* __restrict__ dst_arr,
    const float* __restrict__ msg, const float* __restrict__ a,
    float* __restrict__ agg, float* __restrict__ denom, int E, int N)
{
    const int wid = (int)((blockIdx.x * (size_t)blockDim.x + threadIdx.x) >> 6);
    const int lane = threadIdx.x & 63;
    const int total = E + N;
    if (wid >= total) return;

    int s, d;
    if (wid < E) {
        s = src_arr[wid];  // wave-uniform scalar load
        d = dst_arr[wid];
    } else {
        s = d = wid - E;   // self loop
    }

    const float ms = msg[(size_t)s * OUT_F + lane];
    const float md = msg[(size_t)d * OUT_F + lane];

    float part = md * a[lane] + ms * a[OUT_F + lane];
#pragma unroll
    for (int off = 32; off; off >>= 1) part += __shfl_xor(part, off);

    float e = part;
    e = (e >= 0.f) ? e : 0.01f * e;   // leaky_relu
    const float w = expf(e);

    if (lane == 0) atomicAdd(&denom[d], w);
    atomicAdd(&agg[(size_t)d * OUT_F + lane], ms * w);
}

// --- Kernel 3: out = agg / max(denom, EPS) ---
__global__ __launch_bounds__(256) void normalize_kernel(
    float* __restrict__ out, const float* __restrict__ denom, size_t total)
{
    size_t i = blockIdx.x * (size_t)blockDim.x + threadIdx.x;
    if (i >= total) return;
    float dn = fmaxf(denom[i >> 6], 1e-6f);
    out[i] = out[i] / dn;
}

extern "C" void kernel_launch(void* const* d_in, const int* in_sizes, int n_in,
                              void* d_out, int out_size, void* d_ws, size_t ws_size,
                              hipStream_t stream) {
    const float* x  = (const float*)d_in[0];
    const float* W  = (const float*)d_in[1];
    const float* a  = (const float*)d_in[2];
    const int*   ei = (const int*)d_in[3];
    float* out = (float*)d_out;

    const int IN  = in_sizes[1] / OUT_F;        // 128
    const int N   = in_sizes[0] / IN;           // 100000
    const int E   = in_sizes[3] / 2;            // 1600000
    (void)IN;

    float* msg   = (float*)d_ws;                 // N*64 floats
    float* denom = msg + (size_t)N * OUT_F;      // N floats

    // zero the accumulators (d_out is poisoned; must be deterministic per call)
    hipMemsetAsync(d_out, 0, (size_t)out_size * sizeof(float), stream);
    hipMemsetAsync(denom, 0, (size_t)N * sizeof(float), stream);

    // 1) projection
    gemm_msg_kernel<<<1024, 256, 0, stream>>>(x, W, msg, N);

    // 2) edge pass (one wave per edge, 4 waves/block)
    const int total_edges = E + N;
    const int blocks = (total_edges + 3) / 4;
    edge_kernel<<<blocks, 256, 0, stream>>>(ei, ei + E, msg, a, out, denom, E, N);

    // 3) normalize
    const size_t tot = (size_t)N * OUT_F;
    normalize_kernel<<<(int)((tot + 255) / 256), 256, 0, stream>>>(out, denom, tot);
}

// Round 2
// 411.886 us; speedup vs baseline: 1.6828x; 1.6828x over previous
//
#include <hip/hip_runtime.h>

#define IN_F 128
#define OUT_F 64
#define NEG 0.01f

__device__ __forceinline__ float leaky_exp(float e) {
    e = (e >= 0.f) ? e : NEG * e;
    return expf(e);
}

// --- Kernel 1: msg = x @ W.T, fused alpha[n]=msg[n].a[:64], beta[n]=msg[n].a[64:] ---
__global__ __launch_bounds__(256) void gemm_msg_kernel(
    const float* __restrict__ x, const float* __restrict__ W,
    const float* __restrict__ a,
    float* __restrict__ msg, float* __restrict__ alpha, float* __restrict__ beta,
    int N)
{
    __shared__ float Wt[IN_F * OUT_F];  // 32 KiB, Wt[k*64+o]
    for (int i = threadIdx.x; i < IN_F * OUT_F; i += 256) {
        int k = i >> 6, o = i & 63;
        Wt[i] = W[o * IN_F + k];
    }
    __syncthreads();

    const int wave = threadIdx.x >> 6;
    const int lane = threadIdx.x & 63;
    const float a_lo = a[lane], a_hi = a[OUT_F + lane];
    const int rowstride = gridDim.x * 4;

    for (int row = blockIdx.x * 4 + wave; row < N; row += rowstride) {
        const float4* xr = (const float4*)(x + (size_t)row * IN_F);
        float acc = 0.f;
#pragma unroll
        for (int k4 = 0; k4 < IN_F / 4; ++k4) {
            float4 xv = xr[k4];
            acc += xv.x * Wt[(k4 * 4 + 0) * OUT_F + lane];
            acc += xv.y * Wt[(k4 * 4 + 1) * OUT_F + lane];
            acc += xv.z * Wt[(k4 * 4 + 2) * OUT_F + lane];
            acc += xv.w * Wt[(k4 * 4 + 3) * OUT_F + lane];
        }
        msg[(size_t)row * OUT_F + lane] = acc;
        float pa = acc * a_lo;
        float pb = acc * a_hi;
#pragma unroll
        for (int off = 32; off; off >>= 1) {
            pa += __shfl_xor(pa, off);
            pb += __shfl_xor(pb, off);
        }
        if (lane == 0) { alpha[row] = pa; beta[row] = pb; }
    }
}

// --- Kernel 2: in-degree histogram over real edges ---
__global__ __launch_bounds__(256) void count_kernel(
    const int* __restrict__ dst, int* __restrict__ cnt, int E)
{
    int e = blockIdx.x * 256 + threadIdx.x;
    if (e < E) atomicAdd(&cnt[dst[e]], 1);
}

// --- Scan (hierarchical, 1024/block) ---
__global__ __launch_bounds__(1024) void scan1_kernel(
    const int* __restrict__ cnt, int* __restrict__ offs, int* __restrict__ bsum, int N)
{
    __shared__ int tmp[1024];
    int t = threadIdx.x;
    int i = blockIdx.x * 1024 + t;
    int v = (i < N) ? cnt[i] : 0;
    tmp[t] = v; __syncthreads();
#pragma unroll
    for (int d = 1; d < 1024; d <<= 1) {
        int add = (t >= d) ? tmp[t - d] : 0;
        __syncthreads();
        tmp[t] += add;
        __syncthreads();
    }
    if (i < N) offs[i] = tmp[t] - v;           // block-local exclusive
    if (t == 1023) bsum[blockIdx.x] = tmp[t];  // block total
}

__global__ __launch_bounds__(128) void scan2_kernel(
    const int* __restrict__ bsum, int* __restrict__ bscan, int NB)
{
    __shared__ int tmp[128];
    int t = threadIdx.x;
    int v = (t < NB) ? bsum[t] : 0;
    tmp[t] = v; __syncthreads();
#pragma unroll
    for (int d = 1; d < 128; d <<= 1) {
        int add = (t >= d) ? tmp[t - d] : 0;
        __syncthreads();
        tmp[t] += add;
        __syncthreads();
    }
    if (t < NB) bscan[t] = tmp[t] - v;
}

__global__ __launch_bounds__(1024) void scan3_kernel(
    int* __restrict__ offs, int* __restrict__ cursor,
    const int* __restrict__ bscan, int N, int E)
{
    int i = blockIdx.x * 1024 + threadIdx.x;
    if (i < N) {
        int o = offs[i] + bscan[blockIdx.x];
        offs[i] = o;
        cursor[i] = o;
    }
    if (i == 0) offs[N] = E;
}

// --- Kernel 3: bucket edges by dst; precompute edge weight w ---
__global__ __launch_bounds__(256) void fill_kernel(
    const int* __restrict__ src, const int* __restrict__ dst,
    const float* __restrict__ alpha, const float* __restrict__ beta,
    int* __restrict__ cursor,
    int* __restrict__ src_sorted, float* __restrict__ w_sorted, int E)
{
    int e = blockIdx.x * 256 + threadIdx.x;
    if (e >= E) return;
    int s = src[e], d = dst[e];
    float w = leaky_exp(alpha[d] + beta[s]);
    int pos = atomicAdd(&cursor[d], 1);
    src_sorted[pos] = s;
    w_sorted[pos] = w;
}

// --- Kernel 4: per-node aggregation (no atomics), self-loop + normalize fused ---
__global__ __launch_bounds__(256) void aggregate_kernel(
    const int* __restrict__ offs,
    const int* __restrict__ src_sorted, const float* __restrict__ w_sorted,
    const float* __restrict__ msg,
    const float* __restrict__ alpha, const float* __restrict__ beta,
    float* __restrict__ out, int N)
{
    const int node = blockIdx.x * 4 + (threadIdx.x >> 6);
    if (node >= N) return;
    const int lane = threadIdx.x & 63;

    const float ws = leaky_exp(alpha[node] + beta[node]);  // self-loop
    float acc = ws * msg[(size_t)node * OUT_F + lane];
    float den = ws;

    const int st = offs[node], en = offs[node + 1];
    int j = st;
    for (; j + 3 < en; j += 4) {
        int s0 = src_sorted[j + 0], s1 = src_sorted[j + 1];
        int s2 = src_sorted[j + 2], s3 = src_sorted[j + 3];
        float w0 = w_sorted[j + 0], w1 = w_sorted[j + 1];
        float w2 = w_sorted[j + 2], w3 = w_sorted[j + 3];
        float m0 = msg[(size_t)s0 * OUT_F + lane];
        float m1 = msg[(size_t)s1 * OUT_F + lane];
        float m2 = msg[(size_t)s2 * OUT_F + lane];
        float m3 = msg[(size_t)s3 * OUT_F + lane];
        acc += w0 * m0; acc += w1 * m1; acc += w2 * m2; acc += w3 * m3;
        den += w0 + w1 + w2 + w3;
    }
    for (; j < en; ++j) {
        int s = src_sorted[j];
        float w = w_sorted[j];
        acc += w * msg[(size_t)s * OUT_F + lane];
        den += w;
    }
    out[(size_t)node * OUT_F + lane] = acc / fmaxf(den, 1e-6f);
}

extern "C" void kernel_launch(void* const* d_in, const int* in_sizes, int n_in,
                              void* d_out, int out_size, void* d_ws, size_t ws_size,
                              hipStream_t stream) {
    const float* x  = (const float*)d_in[0];
    const float* W  = (const float*)d_in[1];
    const float* a  = (const float*)d_in[2];
    const int*   ei = (const int*)d_in[3];
    float* out = (float*)d_out;

    const int IN = in_sizes[1] / OUT_F;   // 128
    const int N  = in_sizes[0] / IN;      // 100000
    const int E  = in_sizes[3] / 2;       // 1600000
    const int NB = (N + 1023) / 1024;     // scan blocks

    // workspace layout (all 4-byte elems)
    char* p = (char*)d_ws;
    float* msg        = (float*)p; p += (size_t)N * OUT_F * 4;
    float* alpha      = (float*)p; p += (size_t)N * 4;
    float* beta       = (float*)p; p += (size_t)N * 4;
    int*   cnt        = (int*)p;   p += (size_t)N * 4;
    int*   offs       = (int*)p;   p += (size_t)(N + 1) * 4;
    int*   cursor     = (int*)p;   p += (size_t)N * 4;
    int*   bsum       = (int*)p;   p += (size_t)NB * 4;
    int*   bscan      = (int*)p;   p += (size_t)NB * 4;
    int*   src_sorted = (int*)p;   p += (size_t)E * 4;
    float* w_sorted   = (float*)p; p += (size_t)E * 4;

    const int* esrc = ei;
    const int* edst = ei + E;

    hipMemsetAsync(cnt, 0, (size_t)N * 4, stream);

    gemm_msg_kernel<<<1024, 256, 0, stream>>>(x, W, a, msg, alpha, beta, N);
    count_kernel<<<(E + 255) / 256, 256, 0, stream>>>(edst, cnt, E);
    scan1_kernel<<<NB, 1024, 0, stream>>>(cnt, offs, bsum, N);
    scan2_kernel<<<1, 128, 0, stream>>>(bsum, bscan, NB);
    scan3_kernel<<<NB, 1024, 0, stream>>>(offs, cursor, bscan, N, E);
    fill_kernel<<<(E + 255) / 256, 256, 0, stream>>>(esrc, edst, alpha, beta,
                                                     cursor, src_sorted, w_sorted, E);
    aggregate_kernel<<<(N + 3) / 4, 256, 0, stream>>>(offs, src_sorted, w_sorted,
                                                      msg, alpha, beta, out, N);
}

// Round 3
// 277.448 us; speedup vs baseline: 2.4982x; 1.4846x over previous
//
#include <hip/hip_runtime.h>

#define IN_F 128
#define OUT_F 64
#define NEG 0.01f
#define LDSP 132  // padded row stride (floats): 16B-aligned, breaks bank-conflict

__device__ __forceinline__ float leaky_exp(float e) {
    e = (e >= 0.f) ? e : NEG * e;
    return expf(e);
}

// --- Kernel 1: msg = x @ W.T (tiled, 64 rows x 64 cols per block, full K=128)
// fused alpha[n]=msg[n].a[:64], beta[n]=msg[n].a[64:]
__global__ __launch_bounds__(256) void gemm_msg_kernel(
    const float* __restrict__ x, const float* __restrict__ W,
    const float* __restrict__ a,
    float* __restrict__ msg, float* __restrict__ alpha, float* __restrict__ beta,
    int N)
{
    __shared__ float xs[64 * LDSP];  // 33.8 KiB
    __shared__ float Ws[64 * LDSP];  // 33.8 KiB
    const int tid = threadIdx.x;
    const int base = blockIdx.x * 64;

    // cooperative loads: 2048 float4 each, 8 per thread, coalesced
#pragma unroll
    for (int t = 0; t < 8; ++t) {
        int i = tid + t * 256;      // float4 index
        int c = i >> 5;             // row (0..63)
        int k4 = i & 31;            // float4 within row
        float4 wv = ((const float4*)W)[i];
        *(float4*)&Ws[c * LDSP + k4 * 4] = wv;
    }
#pragma unroll
    for (int t = 0; t < 8; ++t) {
        int i = tid + t * 256;
        int r = i >> 5;
        int k4 = i & 31;
        int row = base + r;
        float4 xv = make_float4(0.f, 0.f, 0.f, 0.f);
        if (row < N) xv = ((const float4*)x)[(size_t)row * (IN_F / 4) + k4];
        *(float4*)&xs[r * LDSP + k4 * 4] = xv;
    }
    __syncthreads();

    const int tx = tid & 15;   // col group (lane bits 0-3)
    const int ty = tid >> 4;   // row group
    const float* xrow = &xs[(ty * 4) * LDSP];
    const float* wrow = &Ws[(tx * 4) * LDSP];

    float acc[4][4] = {};
    for (int k = 0; k < IN_F; k += 4) {
        float4 xv[4], wv[4];
#pragma unroll
        for (int i = 0; i < 4; ++i) xv[i] = *(const float4*)&xrow[i * LDSP + k];
#pragma unroll
        for (int i = 0; i < 4; ++i) wv[i] = *(const float4*)&wrow[i * LDSP + k];
#pragma unroll
        for (int ri = 0; ri < 4; ++ri)
#pragma unroll
            for (int ci = 0; ci < 4; ++ci) {
                acc[ri][ci] += xv[ri].x * wv[ci].x;
                acc[ri][ci] += xv[ri].y * wv[ci].y;
                acc[ri][ci] += xv[ri].z * wv[ci].z;
                acc[ri][ci] += xv[ri].w * wv[ci].w;
            }
    }

    // attention partials for this thread's 4 cols
    float a_lo[4], a_hi[4];
#pragma unroll
    for (int ci = 0; ci < 4; ++ci) {
        a_lo[ci] = a[tx * 4 + ci];
        a_hi[ci] = a[OUT_F + tx * 4 + ci];
    }

#pragma unroll
    for (int ri = 0; ri < 4; ++ri) {
        int row = base + ty * 4 + ri;
        if (row < N) {
            *(float4*)&msg[(size_t)row * OUT_F + tx * 4] =
                make_float4(acc[ri][0], acc[ri][1], acc[ri][2], acc[ri][3]);
        }
        float pa = acc[ri][0] * a_lo[0] + acc[ri][1] * a_lo[1] +
                   acc[ri][2] * a_lo[2] + acc[ri][3] * a_lo[3];
        float pb = acc[ri][0] * a_hi[0] + acc[ri][1] * a_hi[1] +
                   acc[ri][2] * a_hi[2] + acc[ri][3] * a_hi[3];
#pragma unroll
        for (int off = 1; off < 16; off <<= 1) {
            pa += __shfl_xor(pa, off);
            pb += __shfl_xor(pb, off);
        }
        if (tx == 0 && row < N) { alpha[row] = pa; beta[row] = pb; }
    }
}

// --- Kernel 2: in-degree histogram over real edges ---
__global__ __launch_bounds__(256) void count_kernel(
    const int* __restrict__ dst, int* __restrict__ cnt, int E)
{
    int e = blockIdx.x * 256 + threadIdx.x;
    if (e < E) atomicAdd(&cnt[dst[e]], 1);
}

// --- Scan (hierarchical, 1024/block) ---
__global__ __launch_bounds__(1024) void scan1_kernel(
    const int* __restrict__ cnt, int* __restrict__ offs, int* __restrict__ bsum, int N)
{
    __shared__ int tmp[1024];
    int t = threadIdx.x;
    int i = blockIdx.x * 1024 + t;
    int v = (i < N) ? cnt[i] : 0;
    tmp[t] = v; __syncthreads();
#pragma unroll
    for (int d = 1; d < 1024; d <<= 1) {
        int add = (t >= d) ? tmp[t - d] : 0;
        __syncthreads();
        tmp[t] += add;
        __syncthreads();
    }
    if (i < N) offs[i] = tmp[t] - v;           // block-local exclusive
    if (t == 1023) bsum[blockIdx.x] = tmp[t];  // block total
}

__global__ __launch_bounds__(128) void scan2_kernel(
    const int* __restrict__ bsum, int* __restrict__ bscan, int NB)
{
    __shared__ int tmp[128];
    int t = threadIdx.x;
    int v = (t < NB) ? bsum[t] : 0;
    tmp[t] = v; __syncthreads();
#pragma unroll
    for (int d = 1; d < 128; d <<= 1) {
        int add = (t >= d) ? tmp[t - d] : 0;
        __syncthreads();
        tmp[t] += add;
        __syncthreads();
    }
    if (t < NB) bscan[t] = tmp[t] - v;
}

__global__ __launch_bounds__(1024) void scan3_kernel(
    int* __restrict__ offs, int* __restrict__ cursor,
    const int* __restrict__ bscan, int N, int E)
{
    int i = blockIdx.x * 1024 + threadIdx.x;
    if (i < N) {
        int o = offs[i] + bscan[blockIdx.x];
        offs[i] = o;
        cursor[i] = o;
    }
    if (i == 0) offs[N] = E;
}

// --- Kernel 3: bucket edges by dst; precompute edge weight w ---
__global__ __launch_bounds__(256) void fill_kernel(
    const int* __restrict__ src, const int* __restrict__ dst,
    const float* __restrict__ alpha, const float* __restrict__ beta,
    int* __restrict__ cursor,
    int* __restrict__ src_sorted, float* __restrict__ w_sorted, int E)
{
    int e = blockIdx.x * 256 + threadIdx.x;
    if (e >= E) return;
    int s = src[e], d = dst[e];
    float w = leaky_exp(alpha[d] + beta[s]);
    int pos = atomicAdd(&cursor[d], 1);
    src_sorted[pos] = s;
    w_sorted[pos] = w;
}

// --- Kernel 4: per-node aggregation (no atomics), self-loop + normalize fused ---
__global__ __launch_bounds__(256) void aggregate_kernel(
    const int* __restrict__ offs,
    const int* __restrict__ src_sorted, const float* __restrict__ w_sorted,
    const float* __restrict__ msg,
    const float* __restrict__ alpha, const float* __restrict__ beta,
    float* __restrict__ out, int N)
{
    const int node = blockIdx.x * 4 + (threadIdx.x >> 6);
    if (node >= N) return;
    const int lane = threadIdx.x & 63;

    const float ws = leaky_exp(alpha[node] + beta[node]);  // self-loop
    float acc = ws * msg[(size_t)node * OUT_F + lane];
    float den = ws;

    const int st = offs[node], en = offs[node + 1];
    int j = st;
    for (; j + 3 < en; j += 4) {
        int s0 = src_sorted[j + 0], s1 = src_sorted[j + 1];
        int s2 = src_sorted[j + 2], s3 = src_sorted[j + 3];
        float w0 = w_sorted[j + 0], w1 = w_sorted[j + 1];
        float w2 = w_sorted[j + 2], w3 = w_sorted[j + 3];
        float m0 = msg[(size_t)s0 * OUT_F + lane];
        float m1 = msg[(size_t)s1 * OUT_F + lane];
        float m2 = msg[(size_t)s2 * OUT_F + lane];
        float m3 = msg[(size_t)s3 * OUT_F + lane];
        acc += w0 * m0; acc += w1 * m1; acc += w2 * m2; acc += w3 * m3;
        den += w0 + w1 + w2 + w3;
    }
    for (; j < en; ++j) {
        int s = src_sorted[j];
        float w = w_sorted[j];
        acc += w * msg[(size_t)s * OUT_F + lane];
        den += w;
    }
    out[(size_t)node * OUT_F + lane] = acc / fmaxf(den, 1e-6f);
}

extern "C" void kernel_launch(void* const* d_in, const int* in_sizes, int n_in,
                              void* d_out, int out_size, void* d_ws, size_t ws_size,
                              hipStream_t stream) {
    const float* x  = (const float*)d_in[0];
    const float* W  = (const float*)d_in[1];
    const float* a  = (const float*)d_in[2];
    const int*   ei = (const int*)d_in[3];
    float* out = (float*)d_out;

    const int IN = in_sizes[1] / OUT_F;   // 128
    const int N  = in_sizes[0] / IN;      // 100000
    const int E  = in_sizes[3] / 2;       // 1600000
    const int NB = (N + 1023) / 1024;     // scan blocks

    // workspace layout (all 4-byte elems)
    char* p = (char*)d_ws;
    float* msg        = (float*)p; p += (size_t)N * OUT_F * 4;
    float* alpha      = (float*)p; p += (size_t)N * 4;
    float* beta       = (float*)p; p += (size_t)N * 4;
    int*   cnt        = (int*)p;   p += (size_t)N * 4;
    int*   offs       = (int*)p;   p += (size_t)(N + 1) * 4;
    int*   cursor     = (int*)p;   p += (size_t)N * 4;
    int*   bsum       = (int*)p;   p += (size_t)NB * 4;
    int*   bscan      = (int*)p;   p += (size_t)NB * 4;
    int*   src_sorted = (int*)p;   p += (size_t)E * 4;
    float* w_sorted   = (float*)p; p += (size_t)E * 4;

    const int* esrc = ei;
    const int* edst = ei + E;

    hipMemsetAsync(cnt, 0, (size_t)N * 4, stream);

    gemm_msg_kernel<<<(N + 63) / 64, 256, 0, stream>>>(x, W, a, msg, alpha, beta, N);
    count_kernel<<<(E + 255) / 256, 256, 0, stream>>>(edst, cnt, E);
    scan1_kernel<<<NB, 1024, 0, stream>>>(cnt, offs, bsum, N);
    scan2_kernel<<<1, 128, 0, stream>>>(bsum, bscan, NB);
    scan3_kernel<<<NB, 1024, 0, stream>>>(offs, cursor, bscan, N, E);
    fill_kernel<<<(E + 255) / 256, 256, 0, stream>>>(esrc, edst, alpha, beta,
                                                     cursor, src_sorted, w_sorted, E);
    aggregate_kernel<<<(N + 3) / 4, 256, 0, stream>>>(offs, src_sorted, w_sorted,
                                                      msg, alpha, beta, out, N);
}